// Round 1
// baseline (25046.375 us; speedup 1.0000x reference)
//
#include <hip/hip_runtime.h>
#include <math.h>

// Problem constants
#define BQ 256   // batch
#define NN 1024  // nodes
#define EE 256   // embed
#define HH 8     // heads
#define DHD 32   // head dim
#define TS 64    // decode steps
#define SCALE 0.17677669529663687f  // 1/sqrt(32)
#define CLIPC 10.0f

// ---------------------------------------------------------------------------
// Init: zero visited, state init, sum of x over nodes (for masked mean).
// ---------------------------------------------------------------------------
__global__ __launch_bounds__(256) void init_kernel(
    const float* __restrict__ x, const float* __restrict__ cap0,
    float* __restrict__ sum_embed, float* __restrict__ cnt,
    float* __restrict__ capb, int* __restrict__ curb,
    unsigned char* __restrict__ visited)
{
    int b = blockIdx.x, tid = threadIdx.x;
    #pragma unroll
    for (int i = 0; i < 4; i++) visited[b * NN + tid + i * 256] = 0;
    if (tid == 0) { cnt[b] = 1024.0f; capb[b] = cap0[b]; curb[b] = 0; }
    const float* xb = x + (size_t)b * NN * EE + tid;
    float s = 0.f;
    #pragma unroll 8
    for (int n = 0; n < NN; n++) s += xb[(size_t)n * EE];
    sum_embed[b * EE + tid] = s;
}

// ---------------------------------------------------------------------------
// One-time projections: [B*N,256] @ [256, 768] where cols 0..255 = K proj
// (Wqkv cols 256..511), 256..511 = V proj (Wqkv cols 512..767),
// 512..767 = pointer-key proj (Wpk). 64x64 tile, BK=16, 4x4 per thread.
// ---------------------------------------------------------------------------
__global__ __launch_bounds__(256) void proj_kernel(
    const float* __restrict__ x, const float* __restrict__ Wqkv,
    const float* __restrict__ bqkv, const float* __restrict__ Wpk,
    const float* __restrict__ bpk, float* __restrict__ kbuf,
    float* __restrict__ vbuf, float* __restrict__ kpbuf)
{
    __shared__ float As[16][64 + 4];   // [k][m], row stride 68 floats (16B-aligned)
    __shared__ float Ws[16][64];       // [k][c]
    int tid = threadIdx.x;
    int r0 = blockIdx.x * 64;          // row tile (B*N / 64 = 4096)
    int cb = blockIdx.y * 64;          // col tile (768 / 64 = 12)
    int lm = tid >> 2, lk = (tid & 3) * 4;     // A-tile load map
    int wk = tid >> 4, wc = (tid & 15) * 4;    // W-tile load map
    int ty = tid >> 4, tx = tid & 15;
    int m0 = ty * 4, c0 = tx * 4;
    float acc[4][4] = {};
    for (int kk = 0; kk < 256; kk += 16) {
        float4 av = *(const float4*)(x + (size_t)(r0 + lm) * EE + kk + lk);
        As[lk + 0][lm] = av.x; As[lk + 1][lm] = av.y;
        As[lk + 2][lm] = av.z; As[lk + 3][lm] = av.w;
        float4 wv;
        if (cb < 512) wv = *(const float4*)(Wqkv + (size_t)(kk + wk) * 768 + 256 + cb + wc);
        else          wv = *(const float4*)(Wpk  + (size_t)(kk + wk) * EE + (cb - 512) + wc);
        *(float4*)&Ws[wk][wc] = wv;
        __syncthreads();
        #pragma unroll
        for (int k = 0; k < 16; k++) {
            float4 a = *(const float4*)&As[k][m0];
            float4 w = *(const float4*)&Ws[k][c0];
            acc[0][0] += a.x * w.x; acc[0][1] += a.x * w.y; acc[0][2] += a.x * w.z; acc[0][3] += a.x * w.w;
            acc[1][0] += a.y * w.x; acc[1][1] += a.y * w.y; acc[1][2] += a.y * w.z; acc[1][3] += a.y * w.w;
            acc[2][0] += a.z * w.x; acc[2][1] += a.z * w.y; acc[2][2] += a.z * w.z; acc[2][3] += a.z * w.w;
            acc[3][0] += a.w * w.x; acc[3][1] += a.w * w.y; acc[3][2] += a.w * w.z; acc[3][3] += a.w * w.w;
        }
        __syncthreads();
    }
    #pragma unroll
    for (int i = 0; i < 4; i++) {
        int r = r0 + m0 + i;
        int bb = r >> 10, n = r & 1023;
        #pragma unroll
        for (int j = 0; j < 4; j++) {
            int c = cb + c0 + j;
            float val = acc[i][j];
            if (c < 512) val += bqkv[256 + c]; else val += bpk[c - 512];
            if (c < 256) {
                int h = c >> 5, d = c & 31;
                kbuf[(((size_t)bb * HH + h) * NN + n) * DHD + d] = val;
            } else if (c < 512) {
                int c2 = c - 256; int h = c2 >> 5, d = c2 & 31;
                vbuf[(((size_t)bb * HH + h) * NN + n) * DHD + d] = val;
            } else {
                kpbuf[(size_t)r * EE + (c - 512)] = val;
            }
        }
    }
}

// ---------------------------------------------------------------------------
// Step kernel A: vehicle embed -> ve = [mean,sel,cap]@Wc+bc -> q = ve@Wq+bq
// One block per batch row.
// ---------------------------------------------------------------------------
__global__ __launch_bounds__(256) void ve_q_kernel(
    const float* __restrict__ x, const float* __restrict__ sum_embed,
    const float* __restrict__ cnt, const float* __restrict__ capb,
    const int* __restrict__ curb, const float* __restrict__ Wc,
    const float* __restrict__ bc, const float* __restrict__ Wqkv,
    const float* __restrict__ bqkv, float* __restrict__ qout)
{
    int b = blockIdx.x, e = threadIdx.x;
    __shared__ float cvec[513];
    __shared__ float ve[EE];
    int c = curb[b];
    cvec[e] = sum_embed[b * EE + e] / cnt[b];
    cvec[256 + e] = x[((size_t)b * NN + c) * EE + e];
    if (e == 0) cvec[512] = capb[b];
    __syncthreads();
    float acc = bc[e];
    #pragma unroll 4
    for (int i = 0; i < 513; i++) acc += cvec[i] * Wc[i * EE + e];
    ve[e] = acc;
    __syncthreads();
    float q = bqkv[e];
    #pragma unroll 4
    for (int i = 0; i < EE; i++) q += ve[i] * Wqkv[i * 768 + e];
    qout[b * EE + e] = q;
}

// ---------------------------------------------------------------------------
// Step kernel B: per-(b,h) single-query attention with mask -> ctx (pre-Wo).
// ---------------------------------------------------------------------------
__global__ __launch_bounds__(256) void attn_kernel(
    const float* __restrict__ kbuf, const float* __restrict__ vbuf,
    const float* __restrict__ qin, const float* __restrict__ demand,
    const float* __restrict__ capb_, const int* __restrict__ curb_,
    const unsigned char* __restrict__ visited, float* __restrict__ ctxout)
{
    int b = blockIdx.x >> 3, h = blockIdx.x & 7;
    int tid = threadIdx.x;
    __shared__ float qs[DHD];
    __shared__ float p[NN];
    __shared__ float red[8];
    __shared__ float vred[8][DHD];
    __shared__ float s_mx, s_sum;
    if (tid < DHD) qs[tid] = qin[b * EE + h * DHD + tid];
    __syncthreads();
    float capb = capb_[b];
    int curb = curb_[b];
    const float* kb = kbuf + ((size_t)(b * HH + h)) * NN * DHD;
    float mys[4]; bool mym[4]; bool allm = true;
    #pragma unroll
    for (int i = 0; i < 4; i++) {
        int n = tid + i * 256;
        const float4* kr = (const float4*)(kb + (size_t)n * DHD);
        float s = 0.f;
        #pragma unroll
        for (int j = 0; j < 8; j++) {
            float4 kv = kr[j];
            s += qs[4*j+0]*kv.x + qs[4*j+1]*kv.y + qs[4*j+2]*kv.z + qs[4*j+3]*kv.w;
        }
        s *= SCALE;
        bool m = (visited[b * NN + n] != 0) || (demand[b * NN + n] > capb);
        if (n == 0 && curb == 0) m = true;
        mym[i] = m; mys[i] = s;
        allm = allm && m;
    }
    int allmask = __syncthreads_and(allm ? 1 : 0);
    if (allmask && tid == 0) mym[0] = false;   // unmask depot (n=0 owned by tid 0, i=0)
    float lmax = -INFINITY;
    #pragma unroll
    for (int i = 0; i < 4; i++) {
        float s = mym[i] ? -INFINITY : mys[i];
        mys[i] = s;
        lmax = fmaxf(lmax, s);
    }
    #pragma unroll
    for (int o = 32; o > 0; o >>= 1) lmax = fmaxf(lmax, __shfl_down(lmax, o));
    if ((tid & 63) == 0) red[tid >> 6] = lmax;
    __syncthreads();
    if (tid == 0) s_mx = fmaxf(fmaxf(red[0], red[1]), fmaxf(red[2], red[3]));
    __syncthreads();
    float mx = s_mx;
    float lsum = 0.f;
    #pragma unroll
    for (int i = 0; i < 4; i++) {
        float e = (mys[i] == -INFINITY) ? 0.f : expf(mys[i] - mx);
        p[tid + i * 256] = e;
        lsum += e;
    }
    #pragma unroll
    for (int o = 32; o > 0; o >>= 1) lsum += __shfl_down(lsum, o);
    if ((tid & 63) == 0) red[tid >> 6] = lsum;
    __syncthreads();
    if (tid == 0) s_sum = red[0] + red[1] + red[2] + red[3];
    __syncthreads();
    // ctx: thread (chunk, d) accumulates 128 nodes
    int d = tid & 31, chunk = tid >> 5;
    const float* vb = vbuf + ((size_t)(b * HH + h)) * NN * DHD;
    float acc = 0.f;
    int nbase = chunk * 128;
    #pragma unroll 4
    for (int n = nbase; n < nbase + 128; n++)
        acc += p[n] * vb[(size_t)n * DHD + d];
    vred[chunk][d] = acc;
    __syncthreads();
    if (tid < DHD) {
        float s = 0.f;
        #pragma unroll
        for (int c = 0; c < 8; c++) s += vred[c][tid];
        ctxout[b * EE + h * DHD + tid] = s / s_sum;
    }
}

// ---------------------------------------------------------------------------
// Step kernel D: ctx@Wo+bo -> @Wpq+bpq -> u = 10*tanh(qp . kp) -> masked
// softmax -> probs write, argmax (first-index ties, matching np.argmax),
// state update. One block per batch row.
// ---------------------------------------------------------------------------
__global__ __launch_bounds__(256) void prob_kernel(
    const float* __restrict__ ctxin, const float* __restrict__ Wo,
    const float* __restrict__ bo, const float* __restrict__ Wpq,
    const float* __restrict__ bpq, const float* __restrict__ kpbuf,
    const float* __restrict__ demand, const float* __restrict__ x,
    float* __restrict__ capb_, int* __restrict__ curb_,
    unsigned char* __restrict__ visited, float* __restrict__ cnt,
    float* __restrict__ sum_embed, float* __restrict__ probs_out,
    float* __restrict__ route_out, int t)
{
    int b = blockIdx.x, tid = threadIdx.x;
    __shared__ float cs[EE];
    __shared__ float co[EE];
    __shared__ float qp[EE];
    __shared__ float red[8];
    __shared__ int redi[8];
    __shared__ float s_mx, s_sum;
    __shared__ int s_node;
    cs[tid] = ctxin[b * EE + tid];
    __syncthreads();
    float a = bo[tid];
    #pragma unroll 4
    for (int i = 0; i < EE; i++) a += cs[i] * Wo[i * EE + tid];
    co[tid] = a;
    __syncthreads();
    a = bpq[tid];
    #pragma unroll 4
    for (int i = 0; i < EE; i++) a += co[i] * Wpq[i * EE + tid];
    qp[tid] = a;
    __syncthreads();
    float capb = capb_[b];
    int curb = curb_[b];
    const float* kpb = kpbuf + (size_t)b * NN * EE;
    const float4* qpv = (const float4*)qp;
    float myu[4]; bool mym[4]; bool allm = true;
    #pragma unroll
    for (int i = 0; i < 4; i++) {
        int n = tid + i * 256;
        const float4* kr = (const float4*)(kpb + (size_t)n * EE);
        float s = 0.f;
        #pragma unroll 8
        for (int j = 0; j < 64; j++) {
            float4 kv = kr[j];
            float4 qv = qpv[j];
            s += qv.x*kv.x + qv.y*kv.y + qv.z*kv.z + qv.w*kv.w;
        }
        s = CLIPC * tanhf(s);
        bool m = (visited[b * NN + n] != 0) || (demand[b * NN + n] > capb);
        if (n == 0 && curb == 0) m = true;
        mym[i] = m; myu[i] = s;
        allm = allm && m;
    }
    int allmask = __syncthreads_and(allm ? 1 : 0);
    if (allmask && tid == 0) mym[0] = false;
    float lmax = -INFINITY;
    #pragma unroll
    for (int i = 0; i < 4; i++) {
        float s = mym[i] ? -INFINITY : myu[i];
        myu[i] = s;
        lmax = fmaxf(lmax, s);
    }
    #pragma unroll
    for (int o = 32; o > 0; o >>= 1) lmax = fmaxf(lmax, __shfl_down(lmax, o));
    if ((tid & 63) == 0) red[tid >> 6] = lmax;
    __syncthreads();
    if (tid == 0) s_mx = fmaxf(fmaxf(red[0], red[1]), fmaxf(red[2], red[3]));
    __syncthreads();
    float mx = s_mx;
    float pe[4];
    float lsum = 0.f;
    #pragma unroll
    for (int i = 0; i < 4; i++) {
        float e = (myu[i] == -INFINITY) ? 0.f : expf(myu[i] - mx);
        pe[i] = e;
        lsum += e;
    }
    #pragma unroll
    for (int o = 32; o > 0; o >>= 1) lsum += __shfl_down(lsum, o);
    if ((tid & 63) == 0) red[tid >> 6] = lsum;
    __syncthreads();
    if (tid == 0) s_sum = red[0] + red[1] + red[2] + red[3];
    __syncthreads();
    float sm = s_sum;
    float bu = -1.f; int bn = 1 << 30;
    #pragma unroll
    for (int i = 0; i < 4; i++) {
        int n = tid + i * 256;
        float pv = pe[i] / sm;   // matches np division rounding
        probs_out[(size_t)t * BQ * NN + (size_t)b * NN + n] = pv;
        if (pv > bu || (pv == bu && n < bn)) { bu = pv; bn = n; }
    }
    #pragma unroll
    for (int o = 32; o > 0; o >>= 1) {
        float ou = __shfl_down(bu, o);
        int   on = __shfl_down(bn, o);
        if (ou > bu || (ou == bu && on < bn)) { bu = ou; bn = on; }
    }
    if ((tid & 63) == 0) { red[tid >> 6] = bu; redi[tid >> 6] = bn; }
    __syncthreads();
    if (tid == 0) {
        float vv = red[0]; int nd = redi[0];
        for (int w = 1; w < 4; w++)
            if (red[w] > vv || (red[w] == vv && redi[w] < nd)) { vv = red[w]; nd = redi[w]; }
        s_node = nd;
        route_out[t * BQ + b] = (float)nd;
        capb_[b] = capb - demand[b * NN + nd];
        curb_[b] = nd;
        if (nd != 0) {
            visited[b * NN + nd] = 1;
            cnt[b] -= 1.f;
        }
    }
    __syncthreads();
    int node = s_node;
    if (node != 0)
        sum_embed[b * EE + tid] -= x[((size_t)b * NN + node) * EE + tid];
}

// ---------------------------------------------------------------------------
extern "C" void kernel_launch(void* const* d_in, const int* in_sizes, int n_in,
                              void* d_out, int out_size, void* d_ws, size_t ws_size,
                              hipStream_t stream) {
    const float* x      = (const float*)d_in[0];
    const float* demand = (const float*)d_in[1];
    const float* cap0   = (const float*)d_in[2];
    const float* Wc     = (const float*)d_in[3];
    const float* bc     = (const float*)d_in[4];
    const float* Wqkv   = (const float*)d_in[5];
    const float* bqkv   = (const float*)d_in[6];
    const float* Wo     = (const float*)d_in[7];
    const float* bo     = (const float*)d_in[8];
    const float* Wpq    = (const float*)d_in[9];
    const float* bpq    = (const float*)d_in[10];
    const float* Wpk    = (const float*)d_in[11];
    const float* bpk    = (const float*)d_in[12];
    float* out = (float*)d_out;

    float* kbuf      = (float*)d_ws;                 // [B,H,N,dh] 67108864 f
    float* vbuf      = kbuf + 67108864;              // [B,H,N,dh]
    float* kpbuf     = vbuf + 67108864;              // [B,N,E]
    float* sum_embed = kpbuf + 67108864;             // [B,E]
    float* qbuf      = sum_embed + 65536;            // [B,E]
    float* ctxbuf    = qbuf + 65536;                 // [B,E]
    float* cnt       = ctxbuf + 65536;               // [B]
    float* capbuf    = cnt + 256;                    // [B]
    int*   curbuf    = (int*)(capbuf + 256);         // [B]
    unsigned char* visited = (unsigned char*)(curbuf + 256);  // [B,N]

    float* probs_out = out;                          // [T,B,N]
    float* route_out = out + (size_t)TS * BQ * NN;   // [T,B]

    hipLaunchKernelGGL(init_kernel, dim3(BQ), dim3(256), 0, stream,
                       x, cap0, sum_embed, cnt, capbuf, curbuf, visited);
    hipLaunchKernelGGL(proj_kernel, dim3(4096, 12), dim3(256), 0, stream,
                       x, Wqkv, bqkv, Wpk, bpk, kbuf, vbuf, kpbuf);
    for (int t = 0; t < TS; t++) {
        hipLaunchKernelGGL(ve_q_kernel, dim3(BQ), dim3(256), 0, stream,
                           x, sum_embed, cnt, capbuf, curbuf, Wc, bc, Wqkv, bqkv, qbuf);
        hipLaunchKernelGGL(attn_kernel, dim3(BQ * HH), dim3(256), 0, stream,
                           kbuf, vbuf, qbuf, demand, capbuf, curbuf, visited, ctxbuf);
        hipLaunchKernelGGL(prob_kernel, dim3(BQ), dim3(256), 0, stream,
                           ctxbuf, Wo, bo, Wpq, bpq, kpbuf, demand, x,
                           capbuf, curbuf, visited, cnt, sum_embed,
                           probs_out, route_out, t);
    }
}

// Round 2
// 23133.733 us; speedup vs baseline: 1.0827x; 1.0827x over previous
//
#include <hip/hip_runtime.h>
#include <math.h>

// Problem constants
#define BQ 256   // batch
#define NN 1024  // nodes
#define EE 256   // embed
#define HH 8     // heads
#define DHD 32   // head dim
#define TS 64    // decode steps
#define SCALE 0.17677669529663687f  // 1/sqrt(32)
#define CLIPC 10.0f

// ---------------------------------------------------------------------------
// Init: zero visited, state init, sum of x over nodes (for masked mean).
// ---------------------------------------------------------------------------
__global__ __launch_bounds__(256) void init_kernel(
    const float* __restrict__ x, const float* __restrict__ cap0,
    float* __restrict__ sum_embed, float* __restrict__ cnt,
    float* __restrict__ capb, int* __restrict__ curb,
    unsigned char* __restrict__ visited)
{
    int b = blockIdx.x, tid = threadIdx.x;
    #pragma unroll
    for (int i = 0; i < 4; i++) visited[b * NN + tid + i * 256] = 0;
    if (tid == 0) { cnt[b] = 1024.0f; capb[b] = cap0[b]; curb[b] = 0; }
    const float* xb = x + (size_t)b * NN * EE + tid;
    float s = 0.f;
    #pragma unroll 8
    for (int n = 0; n < NN; n++) s += xb[(size_t)n * EE];
    sum_embed[b * EE + tid] = s;
}

// ---------------------------------------------------------------------------
// One-time projections: [B*N,256] @ [256,768]. cols 0..255 -> K (transposed
// out [B,H,D,N]), 256..511 -> V (out [B,H,N,D]), 512..767 -> pointer keys
// (transposed out [B,E,N]). 64x64 tile, BK=16, 4x4 per thread.
// ---------------------------------------------------------------------------
__global__ __launch_bounds__(256) void proj_kernel(
    const float* __restrict__ x, const float* __restrict__ Wqkv,
    const float* __restrict__ bqkv, const float* __restrict__ Wpk,
    const float* __restrict__ bpk, float* __restrict__ kbuf,
    float* __restrict__ vbuf, float* __restrict__ kpbuf)
{
    __shared__ float As[16][68];   // [k][m], stride 68: 2-way max on write (free)
    __shared__ float Ws[16][68];   // [k][c], stride 68: conflict-free f4 writes
    int tid = threadIdx.x;
    int r0 = blockIdx.x * 64;          // row tile (B*N / 64 = 4096)
    int cb = blockIdx.y * 64;          // col tile (768 / 64 = 12)
    int lm = tid >> 2, lk = (tid & 3) * 4;     // A-tile load map
    int wk = tid >> 4, wc = (tid & 15) * 4;    // W-tile load map
    int ty = tid >> 4, tx = tid & 15;
    int m0 = ty * 4, c0 = tx * 4;
    float acc[4][4] = {};
    for (int kk = 0; kk < 256; kk += 16) {
        float4 av = *(const float4*)(x + (size_t)(r0 + lm) * EE + kk + lk);
        As[lk + 0][lm] = av.x; As[lk + 1][lm] = av.y;
        As[lk + 2][lm] = av.z; As[lk + 3][lm] = av.w;
        float4 wv;
        if (cb < 512) wv = *(const float4*)(Wqkv + (size_t)(kk + wk) * 768 + 256 + cb + wc);
        else          wv = *(const float4*)(Wpk  + (size_t)(kk + wk) * EE + (cb - 512) + wc);
        *(float4*)&Ws[wk][wc] = wv;
        __syncthreads();
        #pragma unroll
        for (int k = 0; k < 16; k++) {
            float4 a = *(const float4*)&As[k][m0];
            float4 w = *(const float4*)&Ws[k][c0];
            acc[0][0] += a.x * w.x; acc[0][1] += a.x * w.y; acc[0][2] += a.x * w.z; acc[0][3] += a.x * w.w;
            acc[1][0] += a.y * w.x; acc[1][1] += a.y * w.y; acc[1][2] += a.y * w.z; acc[1][3] += a.y * w.w;
            acc[2][0] += a.z * w.x; acc[2][1] += a.z * w.y; acc[2][2] += a.z * w.z; acc[2][3] += a.z * w.w;
            acc[3][0] += a.w * w.x; acc[3][1] += a.w * w.y; acc[3][2] += a.w * w.z; acc[3][3] += a.w * w.w;
        }
        __syncthreads();
    }
    int bb = r0 >> 10;
    int nbase = (r0 & 1023) + m0;        // node index within batch (f4-aligned)
    int region = cb >> 8;                 // 0:K 1:V 2:KP (tiles never straddle)
    if (region == 0) {
        #pragma unroll
        for (int j = 0; j < 4; j++) {
            int c = cb + c0 + j;
            float bias = bqkv[256 + c];
            int h = c >> 5, d = c & 31;
            float4 o = make_float4(acc[0][j] + bias, acc[1][j] + bias,
                                   acc[2][j] + bias, acc[3][j] + bias);
            *(float4*)(kbuf + (((size_t)bb * HH + h) * DHD + d) * NN + nbase) = o;
        }
    } else if (region == 1) {
        int c2 = cb + c0 - 256;
        int h = c2 >> 5, d0 = c2 & 31;
        #pragma unroll
        for (int i = 0; i < 4; i++) {
            float4 o = make_float4(acc[i][0] + bqkv[512 + c2 + 0],
                                   acc[i][1] + bqkv[512 + c2 + 1],
                                   acc[i][2] + bqkv[512 + c2 + 2],
                                   acc[i][3] + bqkv[512 + c2 + 3]);
            *(float4*)(vbuf + (((size_t)bb * HH + h) * NN + nbase + i) * DHD + d0) = o;
        }
    } else {
        #pragma unroll
        for (int j = 0; j < 4; j++) {
            int e = cb + c0 + j - 512;
            float bias = bpk[e];
            float4 o = make_float4(acc[0][j] + bias, acc[1][j] + bias,
                                   acc[2][j] + bias, acc[3][j] + bias);
            *(float4*)(kpbuf + ((size_t)bb * EE + e) * NN + nbase) = o;
        }
    }
}

// ---------------------------------------------------------------------------
// Step kernel A: vehicle embed -> ve = [mean,sel,cap]@Wc+bc -> q = ve@Wq+bq
// ---------------------------------------------------------------------------
__global__ __launch_bounds__(256) void ve_q_kernel(
    const float* __restrict__ x, const float* __restrict__ sum_embed,
    const float* __restrict__ cnt, const float* __restrict__ capb,
    const int* __restrict__ curb, const float* __restrict__ Wc,
    const float* __restrict__ bc, const float* __restrict__ Wqkv,
    const float* __restrict__ bqkv, float* __restrict__ qout)
{
    int b = blockIdx.x, e = threadIdx.x;
    __shared__ float cvec[513];
    __shared__ float ve[EE];
    int c = curb[b];
    cvec[e] = sum_embed[b * EE + e] / cnt[b];
    cvec[256 + e] = x[((size_t)b * NN + c) * EE + e];
    if (e == 0) cvec[512] = capb[b];
    __syncthreads();
    float acc = bc[e];
    #pragma unroll 4
    for (int i = 0; i < 513; i++) acc += cvec[i] * Wc[i * EE + e];
    ve[e] = acc;
    __syncthreads();
    float q = bqkv[e];
    #pragma unroll 4
    for (int i = 0; i < EE; i++) q += ve[i] * Wqkv[i * 768 + e];
    qout[b * EE + e] = q;
}

// ---------------------------------------------------------------------------
// Step kernel B: per-(b,h) single-query attention with mask -> ctx (pre-Wo).
// K in [B,H,D,N] layout: thread owns 4 consecutive nodes, 1KB/instr loads.
// ---------------------------------------------------------------------------
__global__ __launch_bounds__(256) void attn_kernel(
    const float* __restrict__ kbuf, const float* __restrict__ vbuf,
    const float* __restrict__ qin, const float* __restrict__ demand,
    const float* __restrict__ capb_, const int* __restrict__ curb_,
    const unsigned char* __restrict__ visited, float* __restrict__ ctxout)
{
    int b = blockIdx.x >> 3, h = blockIdx.x & 7;
    int tid = threadIdx.x;
    __shared__ float qs[DHD];
    __shared__ float p[NN];
    __shared__ float red[4];
    __shared__ float vred[8][33];
    __shared__ float s_mx, s_sum;
    if (tid < DHD) qs[tid] = qin[b * EE + h * DHD + tid];
    __syncthreads();
    float capv = capb_[b];
    int cur = curb_[b];
    const float* kb = kbuf + (size_t)(b * HH + h) * DHD * NN;
    int n0 = tid * 4;
    float4 s4 = {0.f, 0.f, 0.f, 0.f};
    #pragma unroll 8
    for (int d = 0; d < DHD; d++) {
        float4 kv = *(const float4*)(kb + (d << 10) + n0);
        float qd = qs[d];
        s4.x = fmaf(qd, kv.x, s4.x);
        s4.y = fmaf(qd, kv.y, s4.y);
        s4.z = fmaf(qd, kv.z, s4.z);
        s4.w = fmaf(qd, kv.w, s4.w);
    }
    float sc[4] = {s4.x * SCALE, s4.y * SCALE, s4.z * SCALE, s4.w * SCALE};
    uchar4 vis = *(const uchar4*)(visited + b * NN + n0);
    float4 dem = *(const float4*)(demand + b * NN + n0);
    bool m[4];
    m[0] = (vis.x != 0) || (dem.x > capv);
    m[1] = (vis.y != 0) || (dem.y > capv);
    m[2] = (vis.z != 0) || (dem.z > capv);
    m[3] = (vis.w != 0) || (dem.w > capv);
    if (tid == 0 && cur == 0) m[0] = true;
    bool allm = m[0] && m[1] && m[2] && m[3];
    int allmask = __syncthreads_and(allm ? 1 : 0);
    if (allmask && tid == 0) m[0] = false;
    float lmax = -INFINITY;
    #pragma unroll
    for (int i = 0; i < 4; i++) {
        sc[i] = m[i] ? -INFINITY : sc[i];
        lmax = fmaxf(lmax, sc[i]);
    }
    #pragma unroll
    for (int o = 32; o > 0; o >>= 1) lmax = fmaxf(lmax, __shfl_down(lmax, o));
    if ((tid & 63) == 0) red[tid >> 6] = lmax;
    __syncthreads();
    if (tid == 0) s_mx = fmaxf(fmaxf(red[0], red[1]), fmaxf(red[2], red[3]));
    __syncthreads();
    float mx = s_mx;
    float4 e4;
    e4.x = (sc[0] == -INFINITY) ? 0.f : expf(sc[0] - mx);
    e4.y = (sc[1] == -INFINITY) ? 0.f : expf(sc[1] - mx);
    e4.z = (sc[2] == -INFINITY) ? 0.f : expf(sc[2] - mx);
    e4.w = (sc[3] == -INFINITY) ? 0.f : expf(sc[3] - mx);
    *(float4*)&p[n0] = e4;
    float lsum = e4.x + e4.y + e4.z + e4.w;
    #pragma unroll
    for (int o = 32; o > 0; o >>= 1) lsum += __shfl_down(lsum, o);
    if ((tid & 63) == 0) red[tid >> 6] = lsum;
    __syncthreads();
    if (tid == 0) s_sum = red[0] + red[1] + red[2] + red[3];
    __syncthreads();
    // ctx: thread (chunk, d) accumulates 128 nodes (2x128B segments/instr)
    int d = tid & 31, chunk = tid >> 5;
    const float* vb = vbuf + (size_t)(b * HH + h) * NN * DHD;
    float acc = 0.f;
    int nbase = chunk * 128;
    #pragma unroll 4
    for (int n = nbase; n < nbase + 128; n++)
        acc += p[n] * vb[(size_t)n * DHD + d];
    vred[chunk][d] = acc;
    __syncthreads();
    if (tid < DHD) {
        float s = 0.f;
        #pragma unroll
        for (int c = 0; c < 8; c++) s += vred[c][tid];
        ctxout[b * EE + h * DHD + tid] = s / s_sum;
    }
}

// ---------------------------------------------------------------------------
// Step kernel D: ctx@Wo+bo -> @Wpq+bpq -> u = 10*tanh(qp . kp) -> masked
// softmax -> probs write, argmax (first-index ties), state update.
// KP in [B,E,N] layout: thread owns 4 consecutive nodes.
// ---------------------------------------------------------------------------
__global__ __launch_bounds__(256) void prob_kernel(
    const float* __restrict__ ctxin, const float* __restrict__ Wo,
    const float* __restrict__ bo, const float* __restrict__ Wpq,
    const float* __restrict__ bpq, const float* __restrict__ kpbuf,
    const float* __restrict__ demand, const float* __restrict__ x,
    float* __restrict__ capb_, int* __restrict__ curb_,
    unsigned char* __restrict__ visited, float* __restrict__ cnt,
    float* __restrict__ sum_embed, float* __restrict__ probs_out,
    float* __restrict__ route_out, int t)
{
    int b = blockIdx.x, tid = threadIdx.x;
    __shared__ float cs[EE];
    __shared__ float co[EE];
    __shared__ float qp[EE];
    __shared__ float red[4];
    __shared__ int redi[4];
    __shared__ float s_mx, s_sum;
    __shared__ int s_node;
    cs[tid] = ctxin[b * EE + tid];
    __syncthreads();
    float a = bo[tid];
    #pragma unroll 4
    for (int i = 0; i < EE; i++) a += cs[i] * Wo[i * EE + tid];
    co[tid] = a;
    __syncthreads();
    a = bpq[tid];
    #pragma unroll 4
    for (int i = 0; i < EE; i++) a += co[i] * Wpq[i * EE + tid];
    qp[tid] = a;
    __syncthreads();
    float capv = capb_[b];
    int cur = curb_[b];
    const float* kpb = kpbuf + (size_t)b * EE * NN;
    int n0 = tid * 4;
    float4 s4 = {0.f, 0.f, 0.f, 0.f};
    #pragma unroll 8
    for (int e = 0; e < EE; e++) {
        float4 kv = *(const float4*)(kpb + (e << 10) + n0);
        float qe = qp[e];
        s4.x = fmaf(qe, kv.x, s4.x);
        s4.y = fmaf(qe, kv.y, s4.y);
        s4.z = fmaf(qe, kv.z, s4.z);
        s4.w = fmaf(qe, kv.w, s4.w);
    }
    float u[4] = {CLIPC * tanhf(s4.x), CLIPC * tanhf(s4.y),
                  CLIPC * tanhf(s4.z), CLIPC * tanhf(s4.w)};
    uchar4 vis = *(const uchar4*)(visited + b * NN + n0);
    float4 dem = *(const float4*)(demand + b * NN + n0);
    bool m[4];
    m[0] = (vis.x != 0) || (dem.x > capv);
    m[1] = (vis.y != 0) || (dem.y > capv);
    m[2] = (vis.z != 0) || (dem.z > capv);
    m[3] = (vis.w != 0) || (dem.w > capv);
    if (tid == 0 && cur == 0) m[0] = true;
    bool allm = m[0] && m[1] && m[2] && m[3];
    int allmask = __syncthreads_and(allm ? 1 : 0);
    if (allmask && tid == 0) m[0] = false;
    float lmax = -INFINITY;
    #pragma unroll
    for (int i = 0; i < 4; i++) {
        u[i] = m[i] ? -INFINITY : u[i];
        lmax = fmaxf(lmax, u[i]);
    }
    #pragma unroll
    for (int o = 32; o > 0; o >>= 1) lmax = fmaxf(lmax, __shfl_down(lmax, o));
    if ((tid & 63) == 0) red[tid >> 6] = lmax;
    __syncthreads();
    if (tid == 0) s_mx = fmaxf(fmaxf(red[0], red[1]), fmaxf(red[2], red[3]));
    __syncthreads();
    float mx = s_mx;
    float pe[4];
    float lsum = 0.f;
    #pragma unroll
    for (int i = 0; i < 4; i++) {
        pe[i] = (u[i] == -INFINITY) ? 0.f : expf(u[i] - mx);
        lsum += pe[i];
    }
    #pragma unroll
    for (int o = 32; o > 0; o >>= 1) lsum += __shfl_down(lsum, o);
    if ((tid & 63) == 0) red[tid >> 6] = lsum;
    __syncthreads();
    if (tid == 0) s_sum = red[0] + red[1] + red[2] + red[3];
    __syncthreads();
    float sm = s_sum;
    float4 pv4;
    float* pv = (float*)&pv4;
    float bu = -1.f; int bn = 1 << 30;
    #pragma unroll
    for (int i = 0; i < 4; i++) {
        pv[i] = pe[i] / sm;   // matches np division rounding
        int n = n0 + i;
        if (pv[i] > bu || (pv[i] == bu && n < bn)) { bu = pv[i]; bn = n; }
    }
    *(float4*)(probs_out + (size_t)t * BQ * NN + (size_t)b * NN + n0) = pv4;
    #pragma unroll
    for (int o = 32; o > 0; o >>= 1) {
        float ou = __shfl_down(bu, o);
        int   on = __shfl_down(bn, o);
        if (ou > bu || (ou == bu && on < bn)) { bu = ou; bn = on; }
    }
    if ((tid & 63) == 0) { red[tid >> 6] = bu; redi[tid >> 6] = bn; }
    __syncthreads();
    if (tid == 0) {
        float vv = red[0]; int nd = redi[0];
        for (int w = 1; w < 4; w++)
            if (red[w] > vv || (red[w] == vv && redi[w] < nd)) { vv = red[w]; nd = redi[w]; }
        s_node = nd;
        route_out[t * BQ + b] = (float)nd;
        capb_[b] = capv - demand[b * NN + nd];
        curb_[b] = nd;
        if (nd != 0) {
            visited[b * NN + nd] = 1;
            cnt[b] -= 1.f;
        }
    }
    __syncthreads();
    int node = s_node;
    if (node != 0)
        sum_embed[b * EE + tid] -= x[((size_t)b * NN + node) * EE + tid];
}

// ---------------------------------------------------------------------------
extern "C" void kernel_launch(void* const* d_in, const int* in_sizes, int n_in,
                              void* d_out, int out_size, void* d_ws, size_t ws_size,
                              hipStream_t stream) {
    const float* x      = (const float*)d_in[0];
    const float* demand = (const float*)d_in[1];
    const float* cap0   = (const float*)d_in[2];
    const float* Wc     = (const float*)d_in[3];
    const float* bc     = (const float*)d_in[4];
    const float* Wqkv   = (const float*)d_in[5];
    const float* bqkv   = (const float*)d_in[6];
    const float* Wo     = (const float*)d_in[7];
    const float* bo     = (const float*)d_in[8];
    const float* Wpq    = (const float*)d_in[9];
    const float* bpq    = (const float*)d_in[10];
    const float* Wpk    = (const float*)d_in[11];
    const float* bpk    = (const float*)d_in[12];
    float* out = (float*)d_out;

    float* kbuf      = (float*)d_ws;                 // [B,H,D,N] 67108864 f
    float* vbuf      = kbuf + 67108864;              // [B,H,N,D]
    float* kpbuf     = vbuf + 67108864;              // [B,E,N]
    float* sum_embed = kpbuf + 67108864;             // [B,E]
    float* qbuf      = sum_embed + 65536;            // [B,E]
    float* ctxbuf    = qbuf + 65536;                 // [B,E]
    float* cnt       = ctxbuf + 65536;               // [B]
    float* capbuf    = cnt + 256;                    // [B]
    int*   curbuf    = (int*)(capbuf + 256);         // [B]
    unsigned char* visited = (unsigned char*)(curbuf + 256);  // [B,N]

    float* probs_out = out;                          // [T,B,N]
    float* route_out = out + (size_t)TS * BQ * NN;   // [T,B]

    hipLaunchKernelGGL(init_kernel, dim3(BQ), dim3(256), 0, stream,
                       x, cap0, sum_embed, cnt, capbuf, curbuf, visited);
    hipLaunchKernelGGL(proj_kernel, dim3(4096, 12), dim3(256), 0, stream,
                       x, Wqkv, bqkv, Wpk, bpk, kbuf, vbuf, kpbuf);
    for (int t = 0; t < TS; t++) {
        hipLaunchKernelGGL(ve_q_kernel, dim3(BQ), dim3(256), 0, stream,
                           x, sum_embed, cnt, capbuf, curbuf, Wc, bc, Wqkv, bqkv, qbuf);
        hipLaunchKernelGGL(attn_kernel, dim3(BQ * HH), dim3(256), 0, stream,
                           kbuf, vbuf, qbuf, demand, capbuf, curbuf, visited, ctxbuf);
        hipLaunchKernelGGL(prob_kernel, dim3(BQ), dim3(256), 0, stream,
                           ctxbuf, Wo, bo, Wpq, bpq, kpbuf, demand, x,
                           capbuf, curbuf, visited, cnt, sum_embed,
                           probs_out, route_out, t);
    }
}